// Round 6
// baseline (575.534 us; speedup 1.0000x reference)
//
#include <hip/hip_runtime.h>
#include <math.h>

#define B_    4096
#define DIN   640
#define DD    128
#define PP    12
#define INV_T 0.25f

typedef __bf16 bft;
typedef __attribute__((ext_vector_type(8))) __bf16 bf16x8;
typedef __attribute__((ext_vector_type(4))) float fx4;

// async 16B global -> LDS (DMA, vmcnt-tracked, no VGPR round trip)
__device__ __forceinline__ void gload16(const float* gp, float* lp) {
  __builtin_amdgcn_global_load_lds(
      (const __attribute__((address_space(1))) unsigned int*)gp,
      (__attribute__((address_space(3))) unsigned int*)lp,
      16, 0, 0);
}

// ---------------------------------------------------------------------------
// prep: split W into bf16 hi/lo AND pack into MFMA-fragment order so embed's
// W loads are single fully-coalesced 16B/lane instructions.
// W1F layout: [ntile 0..7][kc 0..19][hl 0..1][lane 0..63][8 bf16]
//   value(hl, nt, kc, lane=(ln,quad), e) = split(W1[nt*16+ln][kc*32+quad*8+e])
// W2F layout: [ntile 0..7][kc2 0..3][hl][lane][8 bf16] from W2[128][128].
// One thread per 8-elem fragment half. 49152 threads.
// R13 FIX: R12 used `id & 20479` as a modulus — 20480 is NOT a power of two,
// so W1F fragments 4096..16383 were never written (uninit workspace read by
// embed => absmax 2.1e-2). Use explicit subtraction.
// ---------------------------------------------------------------------------
__global__ __launch_bounds__(256) void prep_kernel(
    const float* __restrict__ gw1, const float* __restrict__ pw1,
    const float* __restrict__ gw2, const float* __restrict__ pw2,
    bft* __restrict__ w1fg, bft* __restrict__ w1fp,
    bft* __restrict__ w2fg, bft* __restrict__ w2fp)
{
  int id = blockIdx.x * 256 + threadIdx.x;   // 0 .. 49151
  const float* src;
  bft* dst;
  int nt, kc, hl, lane, kstride;
  if (id < 40960) {                          // W1 g then p
    const bool isg = (id < 20480);
    int f = isg ? id : (id - 20480);         // exact, not a bogus AND-mask
    src = isg ? gw1 : pw1;
    dst = isg ? w1fg : w1fp;
    lane = f & 63;
    int q2 = f >> 6;
    hl = q2 & 1;
    int q3 = q2 >> 1;                        // nt*20 + kc, 0..159
    kc = q3 % 20; nt = q3 / 20;
    kstride = DIN;
    dst += ((size_t)(nt * 20 + kc) * 2 + hl) * 512 + lane * 8;
  } else {                                   // W2 g then p
    const bool isg = (id < 45056);
    int f = isg ? (id - 40960) : (id - 45056);
    src = isg ? gw2 : pw2;
    dst = isg ? w2fg : w2fp;
    lane = f & 63;
    int q2 = f >> 6;
    hl = q2 & 1;
    int q3 = q2 >> 1;                        // nt*4 + kc2, 0..31
    kc = q3 & 3; nt = q3 >> 2;
    kstride = DD;
    dst += ((size_t)(nt * 4 + kc) * 2 + hl) * 512 + lane * 8;
  }
  int ln = lane & 15, quad = lane >> 4;
  const float* s = src + (size_t)(nt * 16 + ln) * kstride + kc * 32 + quad * 8;
#pragma unroll
  for (int e = 0; e < 8; e++) {
    float x = s[e];
    bft h = (bft)x;
    dst[e] = hl ? (bft)(x - (float)h) : h;
  }
}

// ---------------------------------------------------------------------------
// MFMA embed (split-bf16): Y = normalize(relu(X@W1^T+b1)@W2^T+b2).
// R13 = R12 structure (M-step streaming) with the prep fix + max vmcnt tokens.
// Evidence R7/R8/R10/R11: varying barriers, occupancy, prefetch depth all
// left ~100us => limiter is the DRAM access pattern: K-chunked X reads =
// single-use 128B granules at 2560B stride (~1.2 TB/s effective). Fix:
// process 128 rows as 8 steps of 16 rows; each step stages 16 FULL rows
// (40 KB contiguous span) via global_load_lds, computes K=640 completely,
// then phase 2 + normalize + store. X is pure streaming. W pre-packed in
// fragment order (coalesced 16B/lane loads from L2).
// LDS: 2 slots x 40960 B = 81920 (2 blocks/CU). h (8KB) aliases the dead
// part of the current slot. Counted vmcnt: token = min(63, #vmem issued
// after the awaited stage). After STAGE(s): 162 (s=1) / 234 (s>=2) ops
// => 63 (max expressible) is both safe and the weakest wait; step 0 has
// exactly 10 after => 10. Dummy tail stages keep counts uniform.
// Slot lifecycle: stage(s)->slot s&1 issued in step s-2 after barrier D'
// (all waves' A- and h-reads of that slot drained via lgkmcnt(0)+barrier).
// X staging src is XOR-swizzled (chunk c ^ (r&7)) so linear LDS dest +
// swizzled ds_read hits all banks. Op order per output matches the passing
// R0 kernel. p output is b-major [b][l][d] for streaming loss reads.
// Grid: blocks 0..31 = g-stream, 32..415 = p-stream.
// ---------------------------------------------------------------------------
__global__ __launch_bounds__(256, 2) void embed_kernel(
    const float* __restrict__ ebg, const float* __restrict__ ebp,
    const bft* __restrict__ w1fg, const float* __restrict__ b1g,
    const bft* __restrict__ w2fg, const float* __restrict__ b2g,
    const bft* __restrict__ w1fp, const float* __restrict__ b1p,
    const bft* __restrict__ w2fp, const float* __restrict__ b2p,
    float* __restrict__ outg, float* __restrict__ outp)
{
  __shared__ __align__(16) float xsm[2 * 10240];  // 81920 B: 2 slots, 16 rows x 640 f32

  const int t = threadIdx.x;
  const int w = t >> 6, lane = t & 63;
  const int ln = lane & 15, quad = lane >> 4;

  const float *X, *B1, *B2;
  const bft *W1F, *W2F;
  float* Y;
  long m0;
  const bool isg = (blockIdx.x < 32);
  if (isg) {
    X = ebg; W1F = w1fg; B1 = b1g; W2F = w2fg; B2 = b2g;
    Y = outg; m0 = (long)blockIdx.x * 128;
  } else {
    X = ebp; W1F = w1fp; B1 = b1p; W2F = w2fp; B2 = b2p;
    Y = outp; m0 = (long)(blockIdx.x - 32) * 128;
  }

  // staging: 16-B chunk p = w*640 + j*64 + lane covers 0..2559 (16 rows x 160
  // chunks). LDS chunk (r,c) holds global chunk (r, c^(r&7)) [involution].
  int soff[10];
#pragma unroll
  for (int j = 0; j < 10; j++) {
    int pch = w * 640 + j * 64 + lane;
    int r = pch / 160, c = pch - r * 160;
    soff[j] = r * 640 + ((c ^ (r & 7)) << 2);     // dwords within 16-row span
  }

#define STAGE(ts, slot)                                                     \
  {                                                                          \
    const float* xb_ = X + (size_t)(m0 + (ts) * 16) * DIN;                   \
    float* ds_ = xsm + (slot) * 10240;                                       \
    _Pragma("unroll")                                                        \
    for (int j = 0; j < 10; j++)                                             \
      gload16(xb_ + soff[j], ds_ + (w * 640 + j * 64 + lane) * 4);           \
  }

  // hoisted biases (retired before the loop's first waitcnt matters)
  float b1v[2], b2v[8];
#pragma unroll
  for (int nt = 0; nt < 2; nt++) b1v[nt] = B1[w * 32 + nt * 16 + ln];
#pragma unroll
  for (int n8 = 0; n8 < 8; n8++) b2v[n8] = B2[n8 * 16 + ln];

  STAGE(0, 0)
  STAGE(1, 1)

  // Per step s (cur = s&1):
  //  A: waitcnt vmcnt(N) lgkm(0); barrier  [stage(s) ready]
  //  ph1: 20 kc x {2 swizzled ds_read_b128 A, repack hi/lo, 4 W1F loads, 6 MFMA}
  //  B: lgkm(0); barrier                    [all waves' A-reads done]
  //  h-write (bias+relu+split, XOR-swizzled) into slot cur (A region dead)
  //  C: lgkm(0); barrier                    [h visible]
  //  h-read all 4 kc2 (hi/lo) into regs; lgkm(0)
  //  D': barrier                            [slot cur fully dead]
  //  STAGE(s+2 or dummy -> slot cur)        [10 DMAs, in flight across steps]
  //  ph2: 8 ntiles x 4 kc2 x 3 MFMA (full N per wave -> in-wave row sums)
  //  row sums via shfl_xor, rinv, store this wave's 2 ntiles (8 stores)
#define EMBSTEP(s_, VMTOK)                                                   \
  {                                                                          \
    const int cur_ = (s_) & 1;                                               \
    float* xslot = xsm + cur_ * 10240;                                       \
    bft* hhi = (bft*)xslot;                                                  \
    bft* hlo = hhi + 16 * 128;                                               \
    asm volatile("s_waitcnt vmcnt(" VMTOK ") lgkmcnt(0)" ::: "memory");      \
    __builtin_amdgcn_s_barrier();                                            \
    __builtin_amdgcn_sched_barrier(0);                                       \
    fx4 acc0 = (fx4){0.f, 0.f, 0.f, 0.f};                                    \
    fx4 acc1 = (fx4){0.f, 0.f, 0.f, 0.f};                                    \
    const bft* w1b = W1F + (size_t)(2 * w) * 20480 + lane * 8;               \
    const float* xr = xslot + ln * 640;                                      \
    _Pragma("unroll")                                                        \
    for (int kc = 0; kc < 20; kc++) {                                        \
      fx4 x0 = *(const fx4*)(xr + (((kc * 8 + quad * 2)     ^ (ln & 7)) << 2)); \
      fx4 x1 = *(const fx4*)(xr + (((kc * 8 + quad * 2 + 1) ^ (ln & 7)) << 2)); \
      bf16x8 ah, al;                                                         \
      _Pragma("unroll")                                                      \
      for (int j = 0; j < 4; j++) {                                          \
        float xv = x0[j];                                                    \
        bft hh = (bft)xv;                                                    \
        ah[j] = hh;                                                          \
        al[j] = (bft)(xv - (float)hh);                                       \
        float yv = x1[j];                                                    \
        bft hh2 = (bft)yv;                                                   \
        ah[4 + j] = hh2;                                                     \
        al[4 + j] = (bft)(yv - (float)hh2);                                  \
      }                                                                      \
      bf16x8 wh0 = *(const bf16x8*)(w1b + (kc * 2) * 512);                   \
      bf16x8 wl0 = *(const bf16x8*)(w1b + (kc * 2 + 1) * 512);               \
      bf16x8 wh1 = *(const bf16x8*)(w1b + 20480 + (kc * 2) * 512);           \
      bf16x8 wl1 = *(const bf16x8*)(w1b + 20480 + (kc * 2 + 1) * 512);       \
      acc0 = __builtin_amdgcn_mfma_f32_16x16x32_bf16(ah, wh0, acc0, 0, 0, 0); \
      acc0 = __builtin_amdgcn_mfma_f32_16x16x32_bf16(al, wh0, acc0, 0, 0, 0); \
      acc0 = __builtin_amdgcn_mfma_f32_16x16x32_bf16(ah, wl0, acc0, 0, 0, 0); \
      acc1 = __builtin_amdgcn_mfma_f32_16x16x32_bf16(ah, wh1, acc1, 0, 0, 0); \
      acc1 = __builtin_amdgcn_mfma_f32_16x16x32_bf16(al, wh1, acc1, 0, 0, 0); \
      acc1 = __builtin_amdgcn_mfma_f32_16x16x32_bf16(ah, wl1, acc1, 0, 0, 0); \
    }                                                                        \
    asm volatile("s_waitcnt lgkmcnt(0)" ::: "memory");                       \
    __builtin_amdgcn_s_barrier();                                            \
    __builtin_amdgcn_sched_barrier(0);                                       \
    _Pragma("unroll")                                                        \
    for (int nt = 0; nt < 2; nt++) {                                         \
      int ch = w * 4 + nt * 2 + (ln >> 3);                                   \
      int c7 = ln & 7;                                                       \
      fx4 a_ = nt ? acc1 : acc0;                                             \
      _Pragma("unroll")                                                      \
      for (int r = 0; r < 4; r++) {                                          \
        float v = fmaxf(a_[r] + b1v[nt], 0.f);                               \
        bft h = (bft)v;                                                      \
        bft l = (bft)(v - (float)h);                                         \
        int row = quad * 4 + r;                                              \
        int addr = row * 128 + (((ch ^ row) & 15) << 3) + c7;                \
        hhi[addr] = h;                                                       \
        hlo[addr] = l;                                                       \
      }                                                                      \
    }                                                                        \
    asm volatile("s_waitcnt lgkmcnt(0)" ::: "memory");                       \
    __builtin_amdgcn_s_barrier();                                            \
    __builtin_amdgcn_sched_barrier(0);                                       \
    bf16x8 ah2[4], al2[4];                                                   \
    _Pragma("unroll")                                                        \
    for (int kc2 = 0; kc2 < 4; kc2++) {                                      \
      int ch2 = (kc2 * 4 + quad) ^ ln;                                       \
      ah2[kc2] = *(const bf16x8*)&hhi[ln * 128 + (ch2 << 3)];                \
      al2[kc2] = *(const bf16x8*)&hlo[ln * 128 + (ch2 << 3)];                \
    }                                                                        \
    asm volatile("s_waitcnt lgkmcnt(0)" ::: "memory");                       \
    __builtin_amdgcn_s_barrier();                                            \
    __builtin_amdgcn_sched_barrier(0);                                       \
    {                                                                        \
      int ts_ = ((s_) + 2 <= 7) ? (s_) + 2 : (s_);                           \
      STAGE(ts_, cur_)                                                       \
    }                                                                        \
    fx4 o[8];                                                                \
    _Pragma("unroll")                                                        \
    for (int n8 = 0; n8 < 8; n8++)                                           \
      o[n8] = (fx4){b2v[n8], b2v[n8], b2v[n8], b2v[n8]};                     \
    _Pragma("unroll")                                                        \
    for (int n8 = 0; n8 < 8; n8++) {                                         \
      const bft* w2b = W2F + (size_t)n8 * 4096 + lane * 8;                   \
      _Pragma("unroll")                                                      \
      for (int kc2 = 0; kc2 < 4; kc2++) {                                    \
        bf16x8 wh = *(const bf16x8*)(w2b + (kc2 * 2) * 512);                 \
        bf16x8 wl = *(const bf16x8*)(w2b + (kc2 * 2 + 1) * 512);             \
        o[n8] = __builtin_amdgcn_mfma_f32_16x16x32_bf16(ah2[kc2], wh, o[n8], 0, 0, 0); \
        o[n8] = __builtin_amdgcn_mfma_f32_16x16x32_bf16(al2[kc2], wh, o[n8], 0, 0, 0); \
        o[n8] = __builtin_amdgcn_mfma_f32_16x16x32_bf16(ah2[kc2], wl, o[n8], 0, 0, 0); \
      }                                                                      \
    }                                                                        \
    _Pragma("unroll")                                                        \
    for (int r = 0; r < 4; r++) {                                            \
      float sq = 0.f;                                                        \
      _Pragma("unroll")                                                      \
      for (int n8 = 0; n8 < 8; n8++) { float v = o[n8][r]; sq += v * v; }    \
      sq += __shfl_xor(sq, 1, 64);                                           \
      sq += __shfl_xor(sq, 2, 64);                                           \
      sq += __shfl_xor(sq, 4, 64);                                           \
      sq += __shfl_xor(sq, 8, 64);                                           \
      float rinv = 1.0f / sqrtf(sq);                                         \
      long R = m0 + (s_) * 16 + quad * 4 + r;                                \
      _Pragma("unroll")                                                      \
      for (int nt = 0; nt < 2; nt++) {                                       \
        int n8 = 2 * w + nt;                                                 \
        float val = o[n8][r] * rinv;                                         \
        if (isg) {                                                           \
          Y[R * DD + n8 * 16 + ln] = val;                                    \
        } else {                                                             \
          long l_ = R >> 12, b_ = R & 4095;                                  \
          Y[(b_ * PP + l_) * DD + n8 * 16 + ln] = val;                       \
        }                                                                    \
      }                                                                      \
    }                                                                        \
  }

  EMBSTEP(0, "10")
  EMBSTEP(1, "63")
#pragma unroll 1
  for (int s = 2; s < 8; s++) {
    EMBSTEP(s, "63")
  }
}

// ---------------------------------------------------------------------------
// Symmetric KL of one D=128 row pair per 64-lane wave; inputs pre-scaled 1/T.
// sym = sum_i (pu_i - pv_i)*(au_i - av_i)  (LSE terms cancel exactly).
// No max-subtraction: args bounded (|a|<=0.25 dil, [0,1] dcl) -> exp safe.
// ---------------------------------------------------------------------------
__device__ __forceinline__ float sym_kl_row(float au0, float au1, float av0, float av1)
{
  float eu0 = __expf(au0), eu1 = __expf(au1);
  float ev0 = __expf(av0), ev1 = __expf(av1);
  float su = eu0 + eu1, sv = ev0 + ev1;
#pragma unroll
  for (int o = 32; o > 0; o >>= 1) {
    su += __shfl_xor(su, o, 64);
    sv += __shfl_xor(sv, o, 64);
  }
  float ru = 1.0f / su, rv = 1.0f / sv;
  float d0 = au0 - av0, d1 = au1 - av1;
  float part = (eu0 * ru - ev0 * rv) * d0 + (eu1 * ru - ev1 * rv) * d1;
#pragma unroll
  for (int o = 32; o > 0; o >>= 1) part += __shfl_xor(part, o, 64);
  return part;
}

// ---------------------------------------------------------------------------
// Fused loss: one wave per b. p is b-major [b][l][d] -> the 12 patch rows for
// a given b are one contiguous 6 KB span (streaming-friendly).
// ---------------------------------------------------------------------------
__global__ __launch_bounds__(256) void loss_kernel(
    const float* __restrict__ g, const float* __restrict__ p,
    float* __restrict__ pdil, float* __restrict__ pdcl)
{
  __shared__ float wd[4], wc[4];
  int w = threadIdx.x >> 6, lane = threadIdx.x & 63;
  int b = blockIdx.x * 4 + w;
  float2 pl[PP];
  float sx = 0.f, sy = 0.f;
#pragma unroll
  for (int l = 0; l < PP; l++) {
    pl[l] = *(const float2*)&p[((size_t)b * PP + l) * DD + lane * 2];
    sx += pl[l].x; sy += pl[l].y;
  }
  sx *= (1.0f / PP); sy *= (1.0f / PP);
  float2 gv = *(const float2*)&g[(size_t)b * DD + lane * 2];

  float dil = sym_kl_row(gv.x * INV_T, gv.y * INV_T, sx * INV_T, sy * INV_T) * 0.125f;

  float dcl = 0.f;
#pragma unroll
  for (int l = 0; l < PP; l++) {
    float u0 = (gv.x - pl[l].x) * (gv.x - pl[l].x) * INV_T;
    float u1 = (gv.y - pl[l].y) * (gv.y - pl[l].y) * INV_T;
    float v0 = (sx - pl[l].x) * (sx - pl[l].x) * INV_T;
    float v1 = (sy - pl[l].y) * (sy - pl[l].y) * INV_T;
    dcl += sym_kl_row(u0, u1, v0, v1);
  }
  dcl *= (1.0f / 96.0f);

  if (lane == 0) { wd[w] = dil; wc[w] = dcl; }
  __syncthreads();
  if (threadIdx.x == 0) pdil[blockIdx.x] = wd[0] + wd[1] + wd[2] + wd[3];
  if (threadIdx.x == 1) pdcl[blockIdx.x] = wc[0] + wc[1] + wc[2] + wc[3];
}

__global__ __launch_bounds__(256) void final_kernel(const float* __restrict__ pdil,
                                                    const float* __restrict__ pdcl,
                                                    float* __restrict__ out)
{
  __shared__ float red[8];
  int t = threadIdx.x;
  float s0 = 0.f, s1 = 0.f;
  for (int i = t; i < 1024; i += 256) { s0 += pdil[i]; s1 += pdcl[i]; }
#pragma unroll
  for (int o = 32; o > 0; o >>= 1) {
    s0 += __shfl_xor(s0, o, 64);
    s1 += __shfl_xor(s1, o, 64);
  }
  int wid = t >> 6, lane = t & 63;
  if (lane == 0) { red[wid] = s0; red[4 + wid] = s1; }
  __syncthreads();
  if (t == 0) out[0] = red[0] + red[1] + red[2] + red[3];
  if (t == 1) out[1] = red[4] + red[5] + red[6] + red[7];
}

extern "C" void kernel_launch(void* const* d_in, const int* in_sizes, int n_in,
                              void* d_out, int out_size, void* d_ws, size_t ws_size,
                              hipStream_t stream)
{
  const float* ebg = (const float*)d_in[0];
  const float* ebp = (const float*)d_in[1];
  const float* gw1 = (const float*)d_in[3];
  const float* gb1 = (const float*)d_in[4];
  const float* gw2 = (const float*)d_in[5];
  const float* gb2 = (const float*)d_in[6];
  const float* pw1 = (const float*)d_in[7];
  const float* pb1 = (const float*)d_in[8];
  const float* pw2 = (const float*)d_in[9];
  const float* pb2 = (const float*)d_in[10];
  float* out = (float*)d_out;

  float* ws   = (float*)d_ws;
  float* g    = ws;                           // 524288 f
  float* p    = g + (size_t)B_ * DD;          // 6291456 f  (b-major [b][l][d])
  float* pdil = p + (size_t)PP * B_ * DD;     // 1024 f
  float* pdcl = pdil + 1024;                  // 1024 f
  bft* wb   = (bft*)(pdcl + 1024);
  bft* w1fg = wb;                             // 163840 bft (8*20*2*512)
  bft* w1fp = w1fg + 163840;                  // 163840 bft
  bft* w2fg = w1fp + 163840;                  // 32768 bft (8*4*2*512)
  bft* w2fp = w2fg + 32768;                   // 32768 bft

  prep_kernel<<<192, 256, 0, stream>>>(gw1, pw1, gw2, pw2,
                                       w1fg, w1fp, w2fg, w2fp);
  embed_kernel<<<416, 256, 0, stream>>>(ebg, ebp,
                                        w1fg, gb1, w2fg, gb2,
                                        w1fp, pb1, w2fp, pb2,
                                        g, p);
  loss_kernel<<<B_ / 4, 256, 0, stream>>>(g, p, pdil, pdcl);
  final_kernel<<<1, 256, 0, stream>>>(pdil, pdcl, out);
}

// Round 7
// 245.959 us; speedup vs baseline: 2.3400x; 2.3400x over previous
//
#include <hip/hip_runtime.h>
#include <math.h>

#define B_    4096
#define DIN   640
#define DD    128
#define PP    12
#define INV_T 0.25f

typedef __bf16 bft;
typedef __attribute__((ext_vector_type(8))) __bf16 bf16x8;
typedef __attribute__((ext_vector_type(4))) float fx4;

// async 16B global -> LDS (DMA, vmcnt-tracked, no VGPR round trip)
__device__ __forceinline__ void gload16(const float* gp, float* lp) {
  __builtin_amdgcn_global_load_lds(
      (const __attribute__((address_space(1))) unsigned int*)gp,
      (__attribute__((address_space(3))) unsigned int*)lp,
      16, 0, 0);
}

// ---------------------------------------------------------------------------
// prep: split W into bf16 hi/lo AND pack into MFMA-fragment order so embed's
// W loads are single fully-coalesced 16B/lane (1 KB/wave contiguous) loads.
// W1F layout: [ntile 0..7][kc 0..19][hl 0..1][lane 0..63][8 bf16]
//   value(nt,kc,hl,lane=(ln,quad),e) = split_hl(W1[nt*16+ln][kc*32+quad*8+e])
// W2F layout: [ntile 0..7][kc2 0..3][hl][lane][8 bf16] from W2[128][128].
// (R13-fixed indexing: explicit subtraction, no bogus AND-modulus.)
// ---------------------------------------------------------------------------
__global__ __launch_bounds__(256) void prep_kernel(
    const float* __restrict__ gw1, const float* __restrict__ pw1,
    const float* __restrict__ gw2, const float* __restrict__ pw2,
    bft* __restrict__ w1fg, bft* __restrict__ w1fp,
    bft* __restrict__ w2fg, bft* __restrict__ w2fp)
{
  int id = blockIdx.x * 256 + threadIdx.x;   // 0 .. 49151
  const float* src;
  bft* dst;
  int nt, kc, hl, lane, kstride;
  if (id < 40960) {                          // W1 g then p
    const bool isg = (id < 20480);
    int f = isg ? id : (id - 20480);
    src = isg ? gw1 : pw1;
    dst = isg ? w1fg : w1fp;
    lane = f & 63;
    int q2 = f >> 6;
    hl = q2 & 1;
    int q3 = q2 >> 1;                        // nt*20 + kc, 0..159
    kc = q3 % 20; nt = q3 / 20;
    kstride = DIN;
    dst += ((size_t)(nt * 20 + kc) * 2 + hl) * 512 + lane * 8;
  } else {                                   // W2 g then p
    const bool isg = (id < 45056);
    int f = isg ? (id - 40960) : (id - 45056);
    src = isg ? gw2 : pw2;
    dst = isg ? w2fg : w2fp;
    lane = f & 63;
    int q2 = f >> 6;
    hl = q2 & 1;
    int q3 = q2 >> 1;                        // nt*4 + kc2, 0..31
    kc = q3 & 3; nt = q3 >> 2;
    kstride = DD;
    dst += ((size_t)(nt * 4 + kc) * 2 + hl) * 512 + lane * 8;
  }
  int ln = lane & 15, quad = lane >> 4;
  const float* s = src + (size_t)(nt * 16 + ln) * kstride + kc * 32 + quad * 8;
#pragma unroll
  for (int e = 0; e < 8; e++) {
    float x = s[e];
    bft h = (bft)x;
    dst[e] = hl ? (bft)(x - (float)h) : h;
  }
}

// ---------------------------------------------------------------------------
// MFMA embed (split-bf16): Y = normalize(relu(X@W1^T+b1)@W2^T+b2).
// R14 = R10 structure (best measured: 97.5us embed) + two proven deltas:
//  (1) W loads from fragment-packed W1F/W2F (contiguous 1KB/wave vs 16
//      scattered 64B segments; operand VALUES bitwise identical),
//  (2) p output stored b-major [b][l][d] (R13-measured -54us on loss reads).
// R13's 16-row streaming redesign REVERTED: 8x W re-reads (1.9GB via L2)
// thrashed L2 -> FETCH 412MB / WRITE 174MB / 462us. BM=128 restores W
// amortization (W traffic ~266MB from L2).
// Counted-vmcnt K loop: 4-deep X slots (4x16KB aliasing h), raw s_barrier +
// s_waitcnt vmcnt(32) (24 first step); 2-3 chunks in flight across barriers;
// tail dummy loads keep counts constant; full drain before h overwrites xbuf.
// Grid: blocks 0..31 = g-stream, 32..415 = p-stream.
// ---------------------------------------------------------------------------
__global__ __launch_bounds__(256, 2) void embed_kernel(
    const float* __restrict__ ebg, const float* __restrict__ ebp,
    const bft* __restrict__ w1fg, const float* __restrict__ b1g,
    const bft* __restrict__ w2fg, const float* __restrict__ b2g,
    const bft* __restrict__ w1fp, const float* __restrict__ b1p,
    const bft* __restrict__ w2fp, const float* __restrict__ b2p,
    float* __restrict__ outg, float* __restrict__ outp)
{
  __shared__ __align__(16) bft hsm[2 * 128 * 128];  // 65536 B
  float* xbase = (float*)hsm;                 // 4 slots x [128][32] fp32 (16 KB each)
  bft* hhi = hsm;
  bft* hlo = hsm + 128 * 128;
  float* halfsq = (float*)hsm;                // aliased after h dead

  const int t = threadIdx.x;
  const int w = t >> 6, lane = t & 63;
  const int wm = w >> 1, wn = w & 1;
  const int ln = lane & 15, quad = lane >> 4;

  const float *X, *B1, *B2;
  const bft *W1F, *W2F;
  float* Y;
  long m0;
  const bool isg = (blockIdx.x < 32);
  if (isg) {
    X = ebg; W1F = w1fg; B1 = b1g; W2F = w2fg; B2 = b2g;
    Y = outg; m0 = (long)blockIdx.x * 128;
  } else {
    X = ebp; W1F = w1fp; B1 = b1p; W2F = w2fp; B2 = b2p;
    Y = outp; m0 = (long)(blockIdx.x - 32) * 128;
  }

  // staging coords: wave w fills rows w*32..w*32+31; 4 instrs of 64 lanes.
  // lane -> row_local = j*8 + (lane>>3), slot = lane&7, global kq = slot^(row&7)
  const int srow = lane >> 3;                       // 0..7
  const int skq  = (lane & 7) ^ srow;               // swizzled k-quad
  const float* xsrc = X + (size_t)(m0 + w * 32 + srow) * DIN + skq * 4;
  // LDS dest fp32 index for (wave w, instr j): (w*32 + j*8)*32 + lane*4
  const int ldst = w * 32 * 32 + lane * 4;

#define GLX(bufp, k0)                                        \
  _Pragma("unroll")                                          \
  for (int j = 0; j < 4; j++)                                \
    gload16(xsrc + (size_t)j * 8 * DIN + (k0), (bufp) + ldst + j * 8 * 32);

  // MFMA A-fragment read coords: m = wm*64+mt*16+ln, slots s0,s0^1
  const int s0 = ((quad << 1) ^ (ln & 7));

  // fragment-packed W1 pointers: global ntile = wn*4+nt; 20480 bft per ntile
  const bft* p1f[4];
#pragma unroll
  for (int nt = 0; nt < 4; nt++)
    p1f[nt] = W1F + (size_t)(wn * 4 + nt) * 20480 + lane * 8;

  fx4 acc[4][4];
#pragma unroll
  for (int mt = 0; mt < 4; mt++)
#pragma unroll
    for (int nt = 0; nt < 4; nt++) acc[mt][nt] = (fx4){0.f, 0.f, 0.f, 0.f};

  // kcv is the K-chunk index (0..19); 1024 bft per (kc) = hi 512 + lo 512
#define LOADW(wh, wl, kcv)                                 \
  _Pragma("unroll")                                        \
  for (int nt = 0; nt < 4; nt++) {                         \
    wh[nt] = *(const bf16x8*)(p1f[nt] + (kcv) * 1024);     \
    wl[nt] = *(const bf16x8*)(p1f[nt] + (kcv) * 1024 + 512); \
  }

#define PH1CHUNK(bufp, wh, wl)                                                         \
  {                                                                                    \
    bf16x8 ah[4], al[4];                                                               \
    _Pragma("unroll")                                                                  \
    for (int mt = 0; mt < 4; mt++) {                                                   \
      const float* rp = (bufp) + (wm * 64 + mt * 16 + ln) * 32;                        \
      fx4 x0 = *(const fx4*)(rp + s0 * 4);                                             \
      fx4 x1 = *(const fx4*)(rp + (s0 ^ 1) * 4);                                       \
      _Pragma("unroll")                                                                \
      for (int j = 0; j < 4; j++) {                                                    \
        float xv = x0[j];                                                              \
        bft hh = (bft)xv;                                                              \
        ah[mt][j] = hh;                                                                \
        al[mt][j] = (bft)(xv - (float)hh);                                             \
        float yv = x1[j];                                                              \
        bft hh2 = (bft)yv;                                                             \
        ah[mt][4 + j] = hh2;                                                           \
        al[mt][4 + j] = (bft)(yv - (float)hh2);                                        \
      }                                                                                \
    }                                                                                  \
    _Pragma("unroll")                                                                  \
    for (int mt = 0; mt < 4; mt++)                                                     \
      _Pragma("unroll")                                                                \
      for (int nt = 0; nt < 4; nt++) {                                                 \
        acc[mt][nt] = __builtin_amdgcn_mfma_f32_16x16x32_bf16(ah[mt], wh[nt], acc[mt][nt], 0, 0, 0); \
        acc[mt][nt] = __builtin_amdgcn_mfma_f32_16x16x32_bf16(al[mt], wh[nt], acc[mt][nt], 0, 0, 0); \
        acc[mt][nt] = __builtin_amdgcn_mfma_f32_16x16x32_bf16(ah[mt], wl[nt], acc[mt][nt], 0, 0, 0); \
      }                                                                                \
  }

  // ---- phase 1: counted-vmcnt pipelined K loop (20 chunks, 4 LDS slots) ----
  // Issue order: GLX0,GLX1,GLX2,LOADW0 | HS(c): LOADW(c+1)[8], wait, barrier,
  // GLX(c+3)[4], compute(c). At HS(0)'s wait 24 vmem issued after GLX(0);
  // steady state 32 after GLX(c) => vmcnt(24)/vmcnt(32) prove the awaited
  // stage retired while keeping later stages in flight. Tail dummies keep
  // counts constant.
  bf16x8 wha[4], wla[4], whb[4], wlb[4];
  GLX(xbase, 0)                       // chunk 0 -> slot 0
  GLX(xbase + 4096, 32)               // chunk 1 -> slot 1
  GLX(xbase + 8192, 64)               // chunk 2 -> slot 2
  LOADW(wha, wla, 0)

#define HALFSTEP(c, WCH, WCL, WNH, WNL, VMTOK)                              \
  {                                                                          \
    const int kn_ = ((c) + 1 < 20) ? ((c) + 1) : 0;                          \
    LOADW(WNH, WNL, kn_)                                                     \
    asm volatile("s_waitcnt vmcnt(" VMTOK ") lgkmcnt(0)" ::: "memory");      \
    __builtin_amdgcn_s_barrier();                                            \
    __builtin_amdgcn_sched_barrier(0);                                       \
    const int kp_ = ((c) + 3 < 20) ? ((c) + 3) * 32 : 0;                     \
    float* pslot_ = xbase + ((((c) + 3) & 3) << 12);                         \
    GLX(pslot_, kp_)                                                         \
    PH1CHUNK(xbase + ((((c) & 3)) << 12), WCH, WCL)                          \
  }

  HALFSTEP(0, wha, wla, whb, wlb, "24")
  for (int kc = 1; kc < 19; kc += 2) {
    HALFSTEP(kc,     whb, wlb, wha, wla, "32")
    HALFSTEP(kc + 1, wha, wla, whb, wlb, "32")
  }
  HALFSTEP(19, whb, wlb, wha, wla, "32")

  __syncthreads();   // full drain (incl. tail dummy DMAs) before h overwrites xbuf

  // ---- bias1 + relu, split h into LDS (XOR-swizzled 16B chunks) ----
#pragma unroll
  for (int nt = 0; nt < 4; nt++) {
    float bv = B1[wn * 64 + nt * 16 + ln];
    int c8 = wn * 8 + nt * 2 + (ln >> 3);
    int c7 = ln & 7;
#pragma unroll
    for (int mt = 0; mt < 4; mt++) {
#pragma unroll
      for (int r = 0; r < 4; r++) {
        float v = fmaxf(acc[mt][nt][r] + bv, 0.f);
        bft h = (bft)v;
        bft l = (bft)(v - (float)h);
        int m = wm * 64 + mt * 16 + quad * 4 + r;
        int addr = m * 128 + ((c8 ^ (m & 15)) << 3) + c7;
        hhi[addr] = h;
        hlo[addr] = l;
      }
    }
  }

  // ---- phase 2: acc2 = h @ W2^T + b2 (split-bf16), W2F fragment-packed ----
  const bft* p2f[4];
#pragma unroll
  for (int nt = 0; nt < 4; nt++)
    p2f[nt] = W2F + (size_t)(wn * 4 + nt) * 4096 + lane * 8;

  fx4 acc2[4][4];
#pragma unroll
  for (int nt = 0; nt < 4; nt++) {
    float bv = B2[wn * 64 + nt * 16 + ln];
#pragma unroll
    for (int mt = 0; mt < 4; mt++) acc2[mt][nt] = (fx4){bv, bv, bv, bv};
  }

#define LOADW2(wh, wl, kcv)                                \
  _Pragma("unroll")                                        \
  for (int nt = 0; nt < 4; nt++) {                         \
    wh[nt] = *(const bf16x8*)(p2f[nt] + (kcv) * 1024);     \
    wl[nt] = *(const bf16x8*)(p2f[nt] + (kcv) * 1024 + 512); \
  }

#define PH2CHUNK(kcv, wh, wl)                                                          \
  {                                                                                    \
    bf16x8 ah2[4], al2[4];                                                             \
    _Pragma("unroll")                                                                  \
    for (int mt = 0; mt < 4; mt++) {                                                   \
      int m = wm * 64 + mt * 16 + ln;                                                  \
      int c8 = ((kcv) * 4 + quad) ^ (m & 15);                                          \
      ah2[mt] = *(const bf16x8*)&hhi[m * 128 + (c8 << 3)];                             \
      al2[mt] = *(const bf16x8*)&hlo[m * 128 + (c8 << 3)];                             \
    }                                                                                  \
    _Pragma("unroll")                                                                  \
    for (int mt = 0; mt < 4; mt++)                                                     \
      _Pragma("unroll")                                                                \
      for (int nt = 0; nt < 4; nt++) {                                                 \
        acc2[mt][nt] = __builtin_amdgcn_mfma_f32_16x16x32_bf16(ah2[mt], wh[nt], acc2[mt][nt], 0, 0, 0); \
        acc2[mt][nt] = __builtin_amdgcn_mfma_f32_16x16x32_bf16(al2[mt], wh[nt], acc2[mt][nt], 0, 0, 0); \
        acc2[mt][nt] = __builtin_amdgcn_mfma_f32_16x16x32_bf16(ah2[mt], wl[nt], acc2[mt][nt], 0, 0, 0); \
      }                                                                                \
  }

  bf16x8 q2ha[4], q2la[4], q2hb[4], q2lb[4];
  LOADW2(q2ha, q2la, 0)        // issued pre-barrier: barrier hides the latency
  __syncthreads();
  LOADW2(q2hb, q2lb, 1)
  PH2CHUNK(0, q2ha, q2la)
  LOADW2(q2ha, q2la, 2)
  PH2CHUNK(1, q2hb, q2lb)
  LOADW2(q2hb, q2lb, 3)
  PH2CHUNK(2, q2ha, q2la)
  PH2CHUNK(3, q2hb, q2lb)
  __syncthreads();   // h reads done; halfsq may overwrite hsm

  // ---- row L2 normalize + store (g: [b][d]; p: b-major [b][l][d]) ----
#pragma unroll
  for (int mt = 0; mt < 4; mt++) {
#pragma unroll
    for (int r = 0; r < 4; r++) {
      float s = 0.f;
#pragma unroll
      for (int nt = 0; nt < 4; nt++) { float v = acc2[mt][nt][r]; s += v * v; }
      s += __shfl_xor(s, 1, 64);
      s += __shfl_xor(s, 2, 64);
      s += __shfl_xor(s, 4, 64);
      s += __shfl_xor(s, 8, 64);
      if (ln == 0) halfsq[(wm * 64 + mt * 16 + quad * 4 + r) * 2 + wn] = s;
    }
  }
  __syncthreads();
#pragma unroll
  for (int mt = 0; mt < 4; mt++) {
#pragma unroll
    for (int r = 0; r < 4; r++) {
      int row = wm * 64 + mt * 16 + quad * 4 + r;
      float rinv = 1.0f / sqrtf(halfsq[row * 2] + halfsq[row * 2 + 1]);
      long R = m0 + row;
#pragma unroll
      for (int nt = 0; nt < 4; nt++) {
        float val = acc2[mt][nt][r] * rinv;
        int col = wn * 64 + nt * 16 + ln;
        if (isg) {
          Y[R * DD + col] = val;
        } else {
          long l_ = R >> 12, b_ = R & 4095;
          Y[(b_ * PP + l_) * DD + col] = val;
        }
      }
    }
  }
}

// ---------------------------------------------------------------------------
// Symmetric KL of one D=128 row pair per 64-lane wave; inputs pre-scaled 1/T.
// sym = sum_i (pu_i - pv_i)*(au_i - av_i)  (LSE terms cancel exactly).
// No max-subtraction: args bounded (|a|<=0.25 dil, [0,1] dcl) -> exp safe.
// ---------------------------------------------------------------------------
__device__ __forceinline__ float sym_kl_row(float au0, float au1, float av0, float av1)
{
  float eu0 = __expf(au0), eu1 = __expf(au1);
  float ev0 = __expf(av0), ev1 = __expf(av1);
  float su = eu0 + eu1, sv = ev0 + ev1;
#pragma unroll
  for (int o = 32; o > 0; o >>= 1) {
    su += __shfl_xor(su, o, 64);
    sv += __shfl_xor(sv, o, 64);
  }
  float ru = 1.0f / su, rv = 1.0f / sv;
  float d0 = au0 - av0, d1 = au1 - av1;
  float part = (eu0 * ru - ev0 * rv) * d0 + (eu1 * ru - ev1 * rv) * d1;
#pragma unroll
  for (int o = 32; o > 0; o >>= 1) part += __shfl_xor(part, o, 64);
  return part;
}

// ---------------------------------------------------------------------------
// Fused loss: one wave per b. p is b-major [b][l][d] -> the 12 patch rows for
// a given b are one contiguous 6 KB span (streaming-friendly).
// ---------------------------------------------------------------------------
__global__ __launch_bounds__(256) void loss_kernel(
    const float* __restrict__ g, const float* __restrict__ p,
    float* __restrict__ pdil, float* __restrict__ pdcl)
{
  __shared__ float wd[4], wc[4];
  int w = threadIdx.x >> 6, lane = threadIdx.x & 63;
  int b = blockIdx.x * 4 + w;
  float2 pl[PP];
  float sx = 0.f, sy = 0.f;
#pragma unroll
  for (int l = 0; l < PP; l++) {
    pl[l] = *(const float2*)&p[((size_t)b * PP + l) * DD + lane * 2];
    sx += pl[l].x; sy += pl[l].y;
  }
  sx *= (1.0f / PP); sy *= (1.0f / PP);
  float2 gv = *(const float2*)&g[(size_t)b * DD + lane * 2];

  float dil = sym_kl_row(gv.x * INV_T, gv.y * INV_T, sx * INV_T, sy * INV_T) * 0.125f;

  float dcl = 0.f;
#pragma unroll
  for (int l = 0; l < PP; l++) {
    float u0 = (gv.x - pl[l].x) * (gv.x - pl[l].x) * INV_T;
    float u1 = (gv.y - pl[l].y) * (gv.y - pl[l].y) * INV_T;
    float v0 = (sx - pl[l].x) * (sx - pl[l].x) * INV_T;
    float v1 = (sy - pl[l].y) * (sy - pl[l].y) * INV_T;
    dcl += sym_kl_row(u0, u1, v0, v1);
  }
  dcl *= (1.0f / 96.0f);

  if (lane == 0) { wd[w] = dil; wc[w] = dcl; }
  __syncthreads();
  if (threadIdx.x == 0) pdil[blockIdx.x] = wd[0] + wd[1] + wd[2] + wd[3];
  if (threadIdx.x == 1) pdcl[blockIdx.x] = wc[0] + wc[1] + wc[2] + wc[3];
}

__global__ __launch_bounds__(256) void final_kernel(const float* __restrict__ pdil,
                                                    const float* __restrict__ pdcl,
                                                    float* __restrict__ out)
{
  __shared__ float red[8];
  int t = threadIdx.x;
  float s0 = 0.f, s1 = 0.f;
  for (int i = t; i < 1024; i += 256) { s0 += pdil[i]; s1 += pdcl[i]; }
#pragma unroll
  for (int o = 32; o > 0; o >>= 1) {
    s0 += __shfl_xor(s0, o, 64);
    s1 += __shfl_xor(s1, o, 64);
  }
  int wid = t >> 6, lane = t & 63;
  if (lane == 0) { red[wid] = s0; red[4 + wid] = s1; }
  __syncthreads();
  if (t == 0) out[0] = red[0] + red[1] + red[2] + red[3];
  if (t == 1) out[1] = red[4] + red[5] + red[6] + red[7];
}

extern "C" void kernel_launch(void* const* d_in, const int* in_sizes, int n_in,
                              void* d_out, int out_size, void* d_ws, size_t ws_size,
                              hipStream_t stream)
{
  const float* ebg = (const float*)d_in[0];
  const float* ebp = (const float*)d_in[1];
  const float* gw1 = (const float*)d_in[3];
  const float* gb1 = (const float*)d_in[4];
  const float* gw2 = (const float*)d_in[5];
  const float* gb2 = (const float*)d_in[6];
  const float* pw1 = (const float*)d_in[7];
  const float* pb1 = (const float*)d_in[8];
  const float* pw2 = (const float*)d_in[9];
  const float* pb2 = (const float*)d_in[10];
  float* out = (float*)d_out;

  float* ws   = (float*)d_ws;
  float* g    = ws;                           // 524288 f
  float* p    = g + (size_t)B_ * DD;          // 6291456 f  (b-major [b][l][d])
  float* pdil = p + (size_t)PP * B_ * DD;     // 1024 f
  float* pdcl = pdil + 1024;                  // 1024 f
  bft* wb   = (bft*)(pdcl + 1024);
  bft* w1fg = wb;                             // 163840 bft (8*20*2*512)
  bft* w1fp = w1fg + 163840;                  // 163840 bft
  bft* w2fg = w1fp + 163840;                  // 32768 bft (8*4*2*512)
  bft* w2fp = w2fg + 32768;                   // 32768 bft

  prep_kernel<<<192, 256, 0, stream>>>(gw1, pw1, gw2, pw2,
                                       w1fg, w1fp, w2fg, w2fp);
  embed_kernel<<<416, 256, 0, stream>>>(ebg, ebp,
                                        w1fg, gb1, w2fg, gb2,
                                        w1fp, pb1, w2fp, pb2,
                                        g, p);
  loss_kernel<<<B_ / 4, 256, 0, stream>>>(g, p, pdil, pdcl);
  final_kernel<<<1, 256, 0, stream>>>(pdil, pdcl, out);
}